// Round 18
// baseline (417.023 us; speedup 1.0000x reference)
//
#include <hip/hip_runtime.h>

typedef unsigned short u16;
typedef __attribute__((ext_vector_type(4))) unsigned short u16x4;
typedef __attribute__((ext_vector_type(8))) unsigned short u16x8;
typedef __attribute__((ext_vector_type(4))) short s16x4;
typedef __attribute__((ext_vector_type(4))) float f32x4;
typedef __attribute__((ext_vector_type(8))) __bf16 bf16x8;

__device__ __forceinline__ u16 f2bf(float f) {
  union { float f; unsigned int u; } v; v.f = f;
  unsigned int u = v.u;
  unsigned int r = (u + 0x7fffu + ((u >> 16) & 1u)) >> 16;
  return (u16)r;
}
__device__ __forceinline__ u16 f2bf_hw(float f) {  // RNE via HW convert
  return __builtin_bit_cast(u16, (__bf16)f);
}
__device__ __forceinline__ float bf2f(u16 h) {
  union { unsigned int u; float f; } v; v.u = ((unsigned int)h) << 16;
  return v.f;
}
__device__ __forceinline__ f32x4 mfma16(u16x8 a, u16x8 b, f32x4 c) {
  return __builtin_amdgcn_mfma_f32_16x16x32_bf16(
      __builtin_bit_cast(bf16x8, a), __builtin_bit_cast(bf16x8, b), c, 0, 0, 0);
}
// K=16 variant: A/B are 4 bf16 (2 VGPRs)
__device__ __forceinline__ f32x4 mfma16k16(u16x4 a, u16x4 b, f32x4 c) {
  return __builtin_amdgcn_mfma_f32_16x16x16bf16_1k(
      __builtin_bit_cast(s16x4, a), __builtin_bit_cast(s16x4, b), c, 0, 0, 0);
}
// async global->LDS, 16B per lane; LDS dest = wave-uniform base + lane*16
__device__ __forceinline__ void glds16(const void* g, void* l) {
  __builtin_amdgcn_global_load_lds((const __attribute__((address_space(1))) void*)g,
                                   (__attribute__((address_space(3))) void*)l, 16, 0, 0);
}
// bijective XCD-chunked remap: XCD x (= bid&7 empirically) owns a contiguous
// logical-tile range -> blocks sharing operand panels are L2-co-resident.
__device__ __forceinline__ int xcd_chunk(int bid, int nwg) {
  int xcd = bid & 7, idx = bid >> 3;
  int q = nwg >> 3, r = nwg & 7;
  int base = xcd < r ? xcd * (q + 1) : r * (q + 1) + (xcd - r) * q;
  return base + idx;
}
// selected token-block mask from sel[4]: {clip(b0), b1 if >=0} per t.
__device__ __forceinline__ int sel_mask(const int* __restrict__ sel) {
  int m = 0;
#pragma unroll
  for (int tt = 0; tt < 2; ++tt) {
    int a = sel[2 * tt];
    if (a < 0) a = 0;
    m |= 1 << a;
    int b = sel[2 * tt + 1];
    if (b >= 0) m |= 1 << b;
  }
  return m;
}

// ---------------- fused fp32 -> bf16 conversion; his rows sel-predicated ----------
__global__ __launch_bounds__(256) void cvt_all(
    const float* __restrict__ hs, const float* __restrict__ his,
    const float* __restrict__ Wq, const float* __restrict__ Wk,
    const float* __restrict__ Wv, const float* __restrict__ Wo,
    u16* __restrict__ hsb, u16* __restrict__ hib,
    u16* __restrict__ wqb, u16* __restrict__ wkb,
    u16* __restrict__ wvb, u16* __restrict__ wob,
    const int* __restrict__ sel) {
  // f4-chunk boundaries (all /256 -> block-uniform branch)
  const int N0 = 1198080, N1 = 5990400, N2 = 6580224, N3 = 7170048, N4 = 7759872;
  int i = blockIdx.x * 256 + threadIdx.x;
  const float* s; u16* o; int base;
  if (i < N0)      { s = hs;  o = hsb; base = 0;  }
  else if (i < N1) { s = his; o = hib; base = N0; }
  else if (i < N2) { s = Wq;  o = wqb; base = N1; }
  else if (i < N3) { s = Wk;  o = wkb; base = N2; }
  else if (i < N4) { s = Wv;  o = wvb; base = N3; }
  else             { s = Wo;  o = wob; base = N4; }
  int j = i - base;
  if (base == N0) {  // his region: skip rows in unselected token-blocks (never read)
    int row = j / 384;                 // 384 f4 per 1536-col row
    if (!((sel_mask(sel) >> (row / 1560)) & 1)) return;
  }
  float4 v = ((const float4*)s)[j];
  u16x4 r;
  r.x = f2bf(v.x); r.y = f2bf(v.y); r.z = f2bf(v.z); r.w = f2bf(v.w);
  ((u16x4*)o)[j] = r;
}

// ---------------- GEMM: C[M,1536] = A[M,1536] @ W[1536,1536]^T + bias ----------------
// (used for the output projection only now)
template <int OUT, int NBX>  // OUT: 0 = bf16, 1 = f32
__global__ __launch_bounds__(256, 2) void gemm_v2(
    const u16* __restrict__ A, const u16* __restrict__ W,
    const float* __restrict__ bias, void* __restrict__ Cp, int M) {
  const int K = 1536, N = 1536;
  __shared__ __align__(16) u16 gsm[17408];
  u16* As = gsm;
  u16* Bs = gsm + 8192;
  const int tid = threadIdx.x;
  const int lane = tid & 63, wid = tid >> 6;
  const int quad = lane >> 4, l15 = lane & 15;
  const int lg = xcd_chunk(blockIdx.x, gridDim.x);
  const int m0 = (lg / NBX) * 128, n0 = (lg % NBX) * 128;
  const int wm = (wid >> 1) * 64, wn = (wid & 1) * 64;
  f32x4 acc[4][4];
#pragma unroll
  for (int i = 0; i < 4; ++i)
#pragma unroll
    for (int j = 0; j < 4; ++j)
#pragma unroll
      for (int r = 0; r < 4; ++r) acc[i][j][r] = 0.f;

  const int r8 = lane >> 3, c8 = lane & 7;
  const int gch = c8 ^ r8;

  for (int k0 = 0; k0 < K; k0 += 64) {
#pragma unroll
    for (int inst = 0; inst < 4; ++inst) {
      int row = wid * 32 + inst * 8 + r8;
      glds16(A + ((size_t)(m0 + row) * K + k0 + gch * 8), As + (wid * 32 + inst * 8) * 64);
      glds16(W + ((size_t)(n0 + row) * K + k0 + gch * 8), Bs + (wid * 32 + inst * 8) * 64);
    }
    asm volatile("s_waitcnt vmcnt(0)" ::: "memory");
    __syncthreads();
#pragma unroll
    for (int ks = 0; ks < 2; ++ks) {
      u16x8 af[4], bfr[4];
#pragma unroll
      for (int i = 0; i < 4; ++i) {
        int row = wm + i * 16 + l15;
        af[i] = *(const u16x8*)&As[row * 64 + (((ks * 4 + quad) ^ (l15 & 7)) * 8)];
      }
#pragma unroll
      for (int j = 0; j < 4; ++j) {
        int row = wn + j * 16 + l15;
        bfr[j] = *(const u16x8*)&Bs[row * 64 + (((ks * 4 + quad) ^ (l15 & 7)) * 8)];
      }
#pragma unroll
      for (int i = 0; i < 4; ++i)
#pragma unroll
        for (int j = 0; j < 4; ++j) acc[i][j] = mfma16(af[i], bfr[j], acc[i][j]);
    }
    __syncthreads();
  }

#pragma unroll
  for (int i = 0; i < 4; ++i) {
    int row = m0 + wm + i * 16 + quad * 4;
#pragma unroll
    for (int j = 0; j < 4; ++j) {
      int col = n0 + wn + j * 16 + l15;
      float bc = bias[col];
#pragma unroll
      for (int r = 0; r < 4; ++r) {
        if (row + r < M) {
          float v = acc[i][j][r] + bc;
          if (OUT == 1)
            ((float*)Cp)[(size_t)(row + r) * N + col] = v;
          else
            ((u16*)Cp)[(size_t)(row + r) * N + col] = f2bf(v);
        }
      }
    }
  }
}

// ---------------- merged Q + K + V projection GEMM, XCD-balanced -------------------
__global__ __launch_bounds__(256, 2) void gemm_qkv(
    const u16* __restrict__ Aq, const u16* __restrict__ Akv,
    const u16* __restrict__ Wqp, const u16* __restrict__ Wkv,
    const float* __restrict__ bq, const float* __restrict__ bk,
    const float* __restrict__ bv,
    u16* __restrict__ Cq, u16* __restrict__ Ck, u16* __restrict__ Vt,
    const int* __restrict__ sel, int ldt) {
  const int K = 1536;
  __shared__ __align__(16) u16 gsm[17408];
  u16* As = gsm;
  u16* Bs = gsm + 8192;
  const int tid = threadIdx.x;
  const int lane = tid & 63, wid = tid >> 6;
  const int quad = lane >> 4, l15 = lane & 15;
  const int xcd = blockIdx.x & 7, idx = blockIdx.x >> 3;
  const int qn = (xcd < 4) ? 38 : 37;

  const u16 *A, *W;
  const float* bias;
  u16* out;
  int m0, n0, M, vmode;
  if (idx < qn) {  // Q-projection tile (balanced across XCDs)
    int qid = (xcd < 4 ? xcd * 38 : 152 + (xcd - 4) * 37) + idx;  // 0..299
    A = Aq; W = Wqp; bias = bq; out = Cq;
    m0 = (qid / 12) * 128; n0 = (qid % 12) * 128; M = 3120; vmode = 0;
  } else {  // KV-projection
    int kidx = idx - qn;
    if (kidx >= 294) return;           // xcd>=4 spare slot
    int L2 = xcd * 294 + kidx;         // 0..2351
    int qtr = L2 / 588, rem = L2 % 588;   // 588 = 98 m x 6 n per quarter
    int mi = rem / 6;
    m0 = ((mi * 25) % 98) * 128;          // scattered m-panel (bijective, 25⊥98)
    n0 = (qtr * 6 + rem % 6) * 128;       // 0..2944
    {  // selection-aware early exit
      int mask = sel_mask(sel);
      int tb0 = m0 / 1560, tb1 = (m0 + 127) / 1560;
      if (!((mask >> tb0) & 1) && !((mask >> tb1) & 1)) return;
    }
    A = Akv; W = Wkv; M = 12480;
    if (n0 < 1536) { bias = bk; out = Ck; vmode = 0; }
    else { bias = bv; out = nullptr; vmode = 1; }
  }

  const int wm = (wid >> 1) * 64, wn = (wid & 1) * 64;
  f32x4 acc[4][4];
#pragma unroll
  for (int i = 0; i < 4; ++i)
#pragma unroll
    for (int j = 0; j < 4; ++j)
#pragma unroll
      for (int r = 0; r < 4; ++r) acc[i][j][r] = 0.f;

  const int r8 = lane >> 3, c8 = lane & 7;
  const int gch = c8 ^ r8;

  for (int k0 = 0; k0 < K; k0 += 64) {
#pragma unroll
    for (int inst = 0; inst < 4; ++inst) {
      int row = wid * 32 + inst * 8 + r8;
      glds16(A + ((size_t)(m0 + row) * K + k0 + gch * 8), As + (wid * 32 + inst * 8) * 64);
      glds16(W + ((size_t)(n0 + row) * K + k0 + gch * 8), Bs + (wid * 32 + inst * 8) * 64);
    }
    asm volatile("s_waitcnt vmcnt(0)" ::: "memory");
    __syncthreads();
#pragma unroll
    for (int ks = 0; ks < 2; ++ks) {
      u16x8 af[4], bfr[4];
#pragma unroll
      for (int i = 0; i < 4; ++i) {
        int row = wm + i * 16 + l15;
        af[i] = *(const u16x8*)&As[row * 64 + (((ks * 4 + quad) ^ (l15 & 7)) * 8)];
      }
#pragma unroll
      for (int j = 0; j < 4; ++j) {
        int row = wn + j * 16 + l15;
        bfr[j] = *(const u16x8*)&Bs[row * 64 + (((ks * 4 + quad) ^ (l15 & 7)) * 8)];
      }
#pragma unroll
      for (int i = 0; i < 4; ++i)
#pragma unroll
        for (int j = 0; j < 4; ++j) acc[i][j] = mfma16(af[i], bfr[j], acc[i][j]);
    }
    __syncthreads();
  }

  if (vmode == 0) {  // plain bf16 store (Q-proj or K-proj)
#pragma unroll
    for (int i = 0; i < 4; ++i) {
      int row = m0 + wm + i * 16 + quad * 4;
#pragma unroll
      for (int j = 0; j < 4; ++j) {
        int col = n0 + wn + j * 16 + l15;
        float bc = bias[col];
#pragma unroll
        for (int r = 0; r < 4; ++r) {
          if (row + r < M)
            out[(size_t)(row + r) * 1536 + col] = f2bf(acc[i][j][r] + bc);
        }
      }
    }
  } else {  // V-projection: transposed store via LDS
    const int n0v = n0 - 1536;
    u16* Ct = gsm;  // [128 n][136]
#pragma unroll
    for (int i = 0; i < 4; ++i)
#pragma unroll
      for (int j = 0; j < 4; ++j) {
        int nloc = wn + j * 16 + l15;
        float bc = bias[n0v + nloc];
#pragma unroll
        for (int r = 0; r < 4; ++r) {
          int mloc = wm + i * 16 + quad * 4 + r;
          Ct[nloc * 136 + mloc] = f2bf(acc[i][j][r] + bc);
        }
      }
    __syncthreads();
    int n = tid >> 1, half = tid & 1;
#pragma unroll
    for (int e = 0; e < 8; ++e) {
      int mloc = half * 64 + e * 8;
      if (m0 + mloc < M) {
        u16x8 v = *(const u16x8*)&Ct[n * 136 + mloc];
        *(u16x8*)(Vt + (size_t)(n0v + n) * ldt + m0 + mloc) = v;
      }
    }
  }
}

// ---------------- merged RMSNorm + RoPE for Q and K (one launch) -------------------
__global__ __launch_bounds__(192) void norm_rope_all(
    u16* __restrict__ Xq, u16* __restrict__ Xk,
    const float* __restrict__ gq, const float* __restrict__ gk,
    const float* __restrict__ fc, const float* __restrict__ fs,
    const float* __restrict__ fch, const float* __restrict__ fsh,
    float qscale, const int* __restrict__ sel) {
  const int DIMc = 1536;
  int bidr = blockIdx.x;
  u16* X;
  const float *g, *fcp, *fsp;
  float oscale;
  int row;
  if (bidr < 3120) {
    X = Xq; g = gq; fcp = fc; fsp = fs; oscale = qscale; row = bidr;
  } else {
    row = bidr - 3120;
    if (!((sel_mask(sel) >> (row / 1560)) & 1)) return;
    X = Xk; g = gk; fcp = fch; fsp = fsh; oscale = 1.0f;
  }
  int tid = threadIdx.x;
  u16* xr = X + (size_t)row * DIMc + tid * 8;
  u16x8 v = *(const u16x8*)xr;
  float x[8];
  float ss = 0.f;
#pragma unroll
  for (int e = 0; e < 8; ++e) { x[e] = bf2f(v[e]); ss += x[e] * x[e]; }
#pragma unroll
  for (int m = 1; m < 64; m <<= 1) ss += __shfl_xor(ss, m);
  __shared__ float w3[3];
  if ((tid & 63) == 0) w3[tid >> 6] = ss;
  __syncthreads();
  float rs = rsqrtf((w3[0] + w3[1] + w3[2]) * (1.f / 1536.f) + 1e-5f);
  int dhb = (tid * 8) & 127;
  const float* fcr = fcp + (size_t)row * 128 + dhb;
  const float* fsr = fsp + (size_t)row * 128 + dhb;
  float4 c0 = *(const float4*)fcr, c1 = *(const float4*)(fcr + 4);
  float4 s0 = *(const float4*)fsr, s1 = *(const float4*)(fsr + 4);
  const float* gp = g + tid * 8;
  float4 g0 = *(const float4*)gp, g1 = *(const float4*)(gp + 4);
  float cosv[4] = {c0.x, c0.z, c1.x, c1.z};
  float sinv[4] = {s0.y, s0.w, s1.y, s1.w};
  float gv[8] = {g0.x, g0.y, g0.z, g0.w, g1.x, g1.y, g1.z, g1.w};
  u16x8 o;
#pragma unroll
  for (int p = 0; p < 4; ++p) {
    float a = x[2 * p] * rs * gv[2 * p];
    float b = x[2 * p + 1] * rs * gv[2 * p + 1];
    o[2 * p] = f2bf((a * cosv[p] - b * sinv[p]) * oscale);
    o[2 * p + 1] = f2bf((a * sinv[p] + b * cosv[p]) * oscale);
  }
  *(u16x8*)xr = o;
}

// ---------------- block-sparse attention v15: un-bundled R17 -----------------------
// v13 structure + R17's stateless precomputed-base staging addresses (kept; small
// VALU win) with the denominator REVERTED to VALU accumulate + end shuffles (R17's
// ones-MFMA added 4 MFMA/chunk to the co-dominant MFMA pipe and cost 3.5 us).
__global__ __launch_bounds__(256, 3) void attn15(
    const u16* __restrict__ Q, const u16* __restrict__ Kb,
    const u16* __restrict__ VT, const int* __restrict__ sel,
    float* __restrict__ Oacc, float* __restrict__ Lp) {
  const int HWc = 1560, DIMc = 1536, KTt = 12480, NT = 600;
  __shared__ __align__(16) u16 smem[16384];  // Ks0|Ks1|Vt0|Vt1 (8 KB each)
  const int tid = threadIdx.x;
  const int lane = tid & 63, wid = tid >> 6;
  const int quad = lane >> 4, l15 = lane & 15;

  int bid = blockIdx.x;
  int xcd = bid & 7, idx = bid >> 3;   // idx 0..116
  int ug = idx / 13, mt = idx % 13;    // ug 0..8
  int u = xcd + 8 * ug;                // 0..71
  const int h = u / 6;
  const int slot = u % 6;

  // adaptive slot -> (t, seg)
  const int nch0 = (sel[1] >= 0) ? 98 : 49;
  const int nch1 = (sel[3] >= 0) ? 98 : 49;
  const int ns0 = 6 * nch0 / (nch0 + nch1);  // exact integer for all cases
  const int t = (slot < ns0) ? 0 : 1;
  const int si = (slot < ns0) ? slot : slot - ns0;
  const int nseg = (slot < ns0) ? ns0 : 6 - ns0;
  const int m0 = mt * 128;
  const int g = h * 2 + t;

  int s0v = sel[2 * t];
  const int b0 = s0v > 0 ? s0v : 0;
  const int b1 = sel[2 * t + 1];
  const int b1c = b1 >= 0 ? b1 : 0;
  const int nk = (b1 >= 0) ? 2 * HWc : HWc;
  const int nch = (b1 >= 0) ? 98 : 49;
  const int cpseg = (nch + nseg - 1) / nseg;
  const int c0 = si * cpseg;
  const int c1 = (c0 + cpseg < nch) ? c0 + cpseg : nch;

  // Q B-frags: this wave's 32 q rows (2 sub-tiles of 16)
  u16x8 qf[2][4];
#pragma unroll
  for (int qt = 0; qt < 2; ++qt) {
    int qrow = m0 + wid * 32 + qt * 16 + l15;
    if (qrow > HWc - 1) qrow = HWc - 1;
    const u16* qp = Q + (size_t)(t * HWc + qrow) * DIMc + h * 128;
#pragma unroll
    for (int ks = 0; ks < 4; ++ks) qf[qt][ks] = *(const u16x8*)(qp + ks * 32 + quad * 8);
  }

  // precomputed per-lane staging address bases (u16-element units, signed int)
  const int hb = h * 128;
  int klK[2], C0K[2], C1K[2];
#pragma unroll
  for (int n = 0; n < 2; ++n) {
    klK[n] = wid * 8 + n * 4 + (lane >> 4);
    int gc = (lane & 15) ^ (klK[n] & 15);
    int col = hb + gc * 8;
    C0K[n] = b0 * HWc * DIMc + col;
    C1K[n] = (b1c - 1) * HWc * DIMc + col;
  }
  int tgV[2], D0V[2], D1V[2];
#pragma unroll
  for (int n = 0; n < 2; ++n) {
    int dl = wid * 32 + n * 16 + (lane >> 2);
    int gc = (lane & 3) ^ (dl & 3) ^ ((dl >> 2) & 3);
    tgV[n] = gc * 8;
    int rowbase = (hb + dl) * KTt;
    D0V[n] = rowbase + b0 * HWc;
    D1V[n] = rowbase + (b1c - 1) * HWc;
  }

  f32x4 oacc[2][8];  // partial O^T: [q-subtile][d-tile]
#pragma unroll
  for (int qt = 0; qt < 2; ++qt)
#pragma unroll
    for (int m = 0; m < 8; ++m)
#pragma unroll
      for (int r = 0; r < 4; ++r) oacc[qt][m][r] = 0.f;
  float lp[2] = {0.f, 0.f};

  auto stage = [&](int kc, int buf) {
    u16* Ks = smem + buf * 4096;
    u16* Vt = smem + 8192 + buf * 4096;
#pragma unroll
    for (int n = 0; n < 2; ++n) {
      int kg = kc + klK[n];
      int off = kg * DIMc + (kg >= HWc ? C1K[n] : C0K[n]);
      if (kg >= nk) off = C0K[n];
      glds16(Kb + off, Ks + (wid * 8 + n * 4) * 128);
    }
#pragma unroll
    for (int n = 0; n < 2; ++n) {
      int tg = kc + tgV[n];
      int off = tg + (tg >= HWc ? D1V[n] : D0V[n]);
      if (tg >= nk) off = D0V[n];
      glds16(VT + off, Vt + (wid * 32 + n * 16) * 32);
    }
  };

  if (c0 < c1) stage(c0 * 32, 0);

  for (int c = c0; c < c1; ++c) {
    const int buf = (c - c0) & 1;
    u16* Ks = smem + buf * 4096;
    u16* Vt = smem + 8192 + buf * 4096;
    asm volatile("s_waitcnt vmcnt(0)\n\ts_barrier" ::: "memory");
    if (c + 1 < c1) stage((c + 1) * 32, buf ^ 1);

    f32x4 s[2][2];  // [gg][qt]
#pragma unroll
    for (int gg = 0; gg < 2; ++gg)
#pragma unroll
      for (int qt = 0; qt < 2; ++qt)
#pragma unroll
        for (int r = 0; r < 4; ++r) s[gg][qt][r] = 0.f;
#pragma unroll
    for (int ks = 0; ks < 4; ++ks)
#pragma unroll
      for (int gg = 0; gg < 2; ++gg) {
        u16x8 ka = *(const u16x8*)&Ks[(gg * 16 + l15) * 128 + (((ks * 4 + quad) ^ l15) * 8)];
#pragma unroll
        for (int qt = 0; qt < 2; ++qt) s[gg][qt] = mfma16(ka, qf[qt][ks], s[gg][qt]);
      }

    float p[2][2][4];
#pragma unroll
    for (int gg = 0; gg < 2; ++gg)
#pragma unroll
      for (int qt = 0; qt < 2; ++qt)
#pragma unroll
        for (int r = 0; r < 4; ++r) p[gg][qt][r] = exp2f(s[gg][qt][r]);
    if ((c + 1) * 32 > nk) {  // wave-uniform
#pragma unroll
      for (int gg = 0; gg < 2; ++gg)
#pragma unroll
        for (int r = 0; r < 4; ++r) {
          bool bad = c * 32 + gg * 16 + quad * 4 + r >= nk;
          if (bad) {
#pragma unroll
            for (int qt = 0; qt < 2; ++qt) p[gg][qt][r] = 0.f;
          }
        }
    }
    u16x4 pb[2][2];
#pragma unroll
    for (int gg = 0; gg < 2; ++gg)
#pragma unroll
      for (int qt = 0; qt < 2; ++qt)
#pragma unroll
        for (int r = 0; r < 4; ++r) {
          lp[qt] += p[gg][qt][r];
          pb[gg][qt][r] = f2bf_hw(p[gg][qt][r]);
        }

#pragma unroll
    for (int m = 0; m < 8; ++m) {
      int d = m * 16 + l15;
#pragma unroll
      for (int gg = 0; gg < 2; ++gg) {
        int sl = (gg * 2 + (quad >> 1)) ^ (d & 3) ^ ((d >> 2) & 3);
        u16x4 va = *(const u16x4*)&Vt[d * 32 + sl * 8 + (quad & 1) * 4];
#pragma unroll
        for (int qt = 0; qt < 2; ++qt) oacc[qt][m] = mfma16k16(va, pb[gg][qt], oacc[qt][m]);
      }
    }
  }

#pragma unroll
  for (int qt = 0; qt < 2; ++qt) {
    lp[qt] += __shfl_xor(lp[qt], 16);
    lp[qt] += __shfl_xor(lp[qt], 32);
  }
#pragma unroll
  for (int qt = 0; qt < 2; ++qt) {
    int qrow0 = m0 + wid * 32 + qt * 16;  // wave-uniform
    if (qrow0 < HWc) {
      size_t sb = ((size_t)si * NT + g * 25 + (qrow0 >> 6)) * 64 + (qrow0 & 63);
      if (lane < 16 && qrow0 + lane < HWc) Lp[sb + lane] = lp[qt];
      if (qrow0 + l15 < HWc) {
#pragma unroll
        for (int m = 0; m < 8; ++m)
          *(f32x4*)&Oacc[(sb + l15) * 128 + m * 16 + quad * 4] = oacc[qt][m];
      }
    }
  }
}

// ---------------- normalize: O = bf16(sum_seg Oacc / sum_seg Lp) ----------------
__global__ __launch_bounds__(256) void attn_norm(const float* __restrict__ Oacc,
                                                 const float* __restrict__ Lp,
                                                 const int* __restrict__ sel,
                                                 u16* __restrict__ O) {
  const int HWc = 1560, DIMc = 1536, NT = 600;
  int tile = blockIdx.x;  // 600
  int g = tile / 25, mt = tile % 25;
  int h = g >> 1, t = g & 1;
  int m0 = mt * 64;
  int tid = threadIdx.x;
  const int nch0 = (sel[1] >= 0) ? 98 : 49;
  const int nch1 = (sel[3] >= 0) ? 98 : 49;
  const int ns0 = 6 * nch0 / (nch0 + nch1);
  const int nseg = (t == 0) ? ns0 : 6 - ns0;
#pragma unroll
  for (int e = 0; e < 8; ++e) {
    int idx = e * 256 + tid;   // 0..2047 f32x4 slots (64 q x 32)
    int qloc = idx >> 5;
    int d4 = (idx & 31) * 4;
    int q = m0 + qloc;
    if (q < HWc) {
      f32x4 a = {0.f, 0.f, 0.f, 0.f};
      float l = 0.f;
      for (int s = 0; s < nseg; ++s) {
        const size_t sbase = ((size_t)s * NT + tile) * 64 + qloc;
        f32x4 v = *(const f32x4*)&Oacc[sbase * 128 + d4];
#pragma unroll
        for (int r = 0; r < 4; ++r) a[r] += v[r];
        l += Lp[sbase];
      }
      float linv = 1.f / l;
      u16x4 o;
#pragma unroll
      for (int r = 0; r < 4; ++r) o[r] = f2bf(a[r] * linv);
      *(u16x4*)(O + (size_t)(t * HWc + q) * DIMc + h * 128 + d4) = o;
    }
  }
}

extern "C" void kernel_launch(void* const* d_in, const int* in_sizes, int n_in,
                              void* d_out, int out_size, void* d_ws, size_t ws_size,
                              hipStream_t stream) {
  const float* hs  = (const float*)d_in[0];
  const float* his = (const float*)d_in[1];
  const float* fc  = (const float*)d_in[2];
  const float* fs  = (const float*)d_in[3];
  const float* fch = (const float*)d_in[4];
  const float* fsh = (const float*)d_in[5];
  const int*   sel = (const int*)d_in[6];
  const float* Wq  = (const float*)d_in[7];
  const float* bq  = (const float*)d_in[8];
  const float* Wk  = (const float*)d_in[9];
  const float* bk  = (const float*)d_in[10];
  const float* Wv  = (const float*)d_in[11];
  const float* bv  = (const float*)d_in[12];
  const float* Wo  = (const float*)d_in[13];
  const float* bo  = (const float*)d_in[14];
  const float* gq  = (const float*)d_in[15];
  const float* gk  = (const float*)d_in[16];

  const int QT = 3120, KT = 12480, DIMc = 1536;
  u16* p = (u16*)d_ws;
  u16* qb  = p; p += (size_t)QT * DIMc;
  u16* kb2 = p; p += (size_t)KT * DIMc;
  u16* vt  = p; p += (size_t)DIMc * KT;   // V^T [1536][12480]
  u16* ab  = p; p += (size_t)QT * DIMc;
  u16* wob = p; p += (size_t)DIMc * DIMc;
  u16* scratch = p;
  u16* hsb = scratch;
  u16* hib = hsb + (size_t)QT * DIMc;
  u16* wqb = hib + (size_t)KT * DIMc;
  u16* wkb = wqb + (size_t)DIMc * DIMc;   // wkb and wvb adjacent -> stacked [3072][1536]
  u16* wvb = wkb + (size_t)DIMc * DIMc;
  float* oaccb = (float*)scratch;                      // f32 [4][600][64][128]
  float* lpb   = oaccb + (size_t)4 * 600 * 64 * 128;   // f32 [4][600][64]

  cvt_all<<<dim3(32616), 256, 0, stream>>>(hs, his, Wq, Wk, Wv, Wo,
                                           hsb, hib, wqb, wkb, wvb, wob, sel);

  gemm_qkv<<<dim3(2656), 256, 0, stream>>>(hsb, hib, wqb, wkb, bq, bk, bv,
                                           qb, kb2, vt, sel, KT);

  const float qscale = (float)(0.08838834764831845 * 1.4426950408889634);
  norm_rope_all<<<dim3(QT + KT), 192, 0, stream>>>(qb, kb2, gq, gk, fc, fs, fch, fsh,
                                                   qscale, sel);

  // attn15 clobbers hsb/hib/wq/wk/wv (all dead by now); wob stays live for the final gemm.
  attn15<<<dim3(936), 256, 0, stream>>>(qb, kb2, vt, sel, oaccb, lpb);
  attn_norm<<<dim3(600), 256, 0, stream>>>(oaccb, lpb, sel, ab);

  gemm_v2<1, 12><<<dim3(300), 256, 0, stream>>>(ab, wob, bo, d_out, QT);
}